// Round 4
// baseline (525.393 us; speedup 1.0000x reference)
//
#include <hip/hip_runtime.h>

// BSplineBasis: T=262144, K=512, DEGREE=3. Output (T,512) fp32 = 512 MiB,
// only 4 nonzeros per row; output is poisoned in the timed region so all
// 512 MiB must be rewritten. Floor = 512 MiB / 6.2 TB/s (measured blit rate)
// ~= 86 us, plus ~345-430 us of harness poison fills we cannot touch.
//
// This version mimics the rocclr fill blit structure: 2048 persistent blocks
// (8/CU), each owning 128 contiguous rows. Phase 1 computes all 128 rows'
// 4 nonzero values + start column into LDS (one barrier). Phase 2 is a long
// run of 64 back-to-back nontemporal dwordx4 stores per thread -- no block
// churn, no further barriers, maximal memory-level parallelism.

namespace {
constexpr int K_N  = 512;    // basis count (output columns)
constexpr int NKN  = 516;    // K + DEGREE + 1 knots
constexpr int DEG  = 3;
constexpr float EPSF = 1e-6f;
constexpr int ROWS = 128;    // rows per block
constexpr int BLK  = 256;    // threads per block (4 waves)

typedef float f32x4 __attribute__((ext_vector_type(4)));
}

__global__ __launch_bounds__(BLK)
void bspline_dense_kernel(const float* __restrict__ t_arr,
                          const float* __restrict__ knots,
                          float* __restrict__ out)
{
    __shared__ float kv[NKN];
    __shared__ float vals[ROWS][4];
    __shared__ int   j0s[ROWS];

    const int tid = threadIdx.x;
    for (int i = tid; i < NKN; i += BLK) kv[i] = knots[i];
    __syncthreads();

    const int row_base = blockIdx.x * ROWS;

    // Phase 1: threads 0..127 each compute one row's 4 nonzero basis values.
    // Arithmetic identical to the harness-verified kernel.
    if (tid < ROWS) {
        const float t = t_arr[row_base + tid];
        int j0 = -16;                       // sentinel: all-zero row
        float N0 = 0.f, N1 = 0.f, N2 = 0.f, N3 = 0.f;
        // Reference: t >= kv[512] (t >= 1.0) yields an all-zero row.
        if (t < kv[K_N]) {
            // Largest s in [3, 511] with kv[s] <= t (same fp32 compares as ref).
            int lo = DEG, hi = K_N - 1;
            while (lo < hi) {
                const int mid = (lo + hi + 1) >> 1;
                if (t >= kv[mid]) lo = mid; else hi = mid - 1;
            }
            const int s = lo;
            float N[4] = {1.f, 0.f, 0.f, 0.f};
            #pragma unroll
            for (int d = 1; d <= DEG; ++d) {
                float nn[4];
                #pragma unroll
                for (int k = 0; k <= d; ++k) {
                    const int j = s - d + k;
                    const float left  = (k >= 1)     ? N[k - 1] : 0.f;
                    const float right = (k <= d - 1) ? N[k]     : 0.f;
                    const float den1 = kv[j + d]     - kv[j];
                    const float den2 = kv[j + d + 1] - kv[j + 1];
                    const float c1 = (den1 >= EPSF) ? (t - kv[j]) / den1 : 0.f;
                    const float c2 = (den2 >= EPSF) ? (kv[j + d + 1] - t) / den2 : 0.f;
                    nn[k] = c1 * left + c2 * right;
                }
                #pragma unroll
                for (int k = 0; k <= d; ++k) N[k] = nn[k];
            }
            j0 = s - DEG;
            N0 = N[0]; N1 = N[1]; N2 = N[2]; N3 = N[3];
        }
        j0s[tid] = j0;
        vals[tid][0] = N0; vals[tid][1] = N1;
        vals[tid][2] = N2; vals[tid][3] = N3;
    }
    __syncthreads();

    // Phase 2: 128 rows x 128 float4 = 16384 float4 / 256 threads = 64 iters
    // of pure, fully-coalesced nontemporal stores. r = idx>>7 is wave-uniform
    // (each wave covers half a row per iteration); t is sorted so the overlap
    // branch is wave-coherent and almost always takes the zero path.
    f32x4* out4 = reinterpret_cast<f32x4*>(out + (size_t)row_base * K_N);
    const int c = (tid & 127) << 2;        // first column of this float4
    const f32x4 zero4 = {0.f, 0.f, 0.f, 0.f};
    constexpr int ITERS = ROWS * (K_N / 4) / BLK;   // 64
    #pragma unroll 8
    for (int it = 0; it < ITERS; ++it) {
        const int idx = it * BLK + tid;
        const int r   = idx >> 7;            // wave-uniform row
        const int rel = c - j0s[r];          // LDS broadcast read
        // Window [j0, j0+3] overlaps columns [c, c+3] iff -3 <= rel <= 3.
        // j0 = -16 sentinel => rel >= 16 => zero path.
        if (rel < -3 || rel > 3) {
            __builtin_nontemporal_store(zero4, &out4[idx]);
        } else {
            f32x4 e;
            #pragma unroll
            for (int k = 0; k < 4; ++k) {
                const int m = rel + k;               // value index for col c+k
                const float v = vals[r][m & 3];      // safe LDS read
                e[k] = (m >= 0 && m <= 3) ? v : 0.f;
            }
            __builtin_nontemporal_store(e, &out4[idx]);
        }
    }
}

extern "C" void kernel_launch(void* const* d_in, const int* in_sizes, int n_in,
                              void* d_out, int out_size, void* d_ws, size_t ws_size,
                              hipStream_t stream) {
    const float* t_arr = (const float*)d_in[0];
    const float* knots = (const float*)d_in[1];
    float* out = (float*)d_out;
    const int n_rows = in_sizes[0];              // 262144, divisible by ROWS
    dim3 grid(n_rows / ROWS);                    // 2048 blocks = 8 per CU
    hipLaunchKernelGGL(bspline_dense_kernel, grid, dim3(BLK), 0, stream,
                       t_arr, knots, out);
}